// Round 7
// baseline (1804.075 us; speedup 1.0000x reference)
//
#include <hip/hip_runtime.h>
#include <math.h>

// B=256, T=2048, D=64, U=128, 4U=512, COND=32
namespace {
constexpr int kB    = 256;
constexpr int kT    = 2048;
constexpr int kD    = 64;
constexpr int kU    = 128;
constexpr int kCOND = 32;
constexpr int kCH   = 16;                      // timesteps per x chunk
constexpr int kXGS  = 522;                     // xg row stride (floats);
// 4*522 mod 32 = 8 -> the 4 quads' store rows land on banks {0,8,16,24}:
// worst case 2-way, which is free (m136). (520 gave 0 -> 4-way, 8.4M conflicts.)
constexpr int kXgSlot = kCH * kXGS * 4;        // 33408 B
constexpr int kXgOff  = 0;                     // xg: 2 slots
constexpr int kXsOff  = 2 * kXgSlot;           // 66816; xs: 2 x [16][64] f16 swz
constexpr int kXsSlot = kCH * kD * 2;          // 2048 B
constexpr int kHOff   = kXsOff + 2 * kXsSlot;  // 70912; hbuf: 2 x [128] f16
constexpr int kLds    = kHOff + 512;           // 71424
}

typedef _Float16 f16x8 __attribute__((ext_vector_type(8)));
typedef _Float16 f16x2 __attribute__((ext_vector_type(2)));
typedef float    f32x4 __attribute__((ext_vector_type(4)));

__device__ __forceinline__ float sig_(float z) {
    return 1.0f / (1.0f + __expf(-z));
}
__device__ __forceinline__ float tanh_(float z) {
    float ez = __expf(-2.0f * fabsf(z));
    float t  = (1.0f - ez) / (1.0f + ez);
    return copysignf(t, z);
}
// pin a 16B fragment so the allocator cannot rematerialize its global loads
__device__ __forceinline__ void pin4_(f16x8& w) {
    f32x4 t = __builtin_bit_cast(f32x4, w);
    asm volatile("" : "+v"(t));
    w = __builtin_bit_cast(f16x8, t);
}

// One WG (512 thr = 8 waves) per batch element, persistent over T steps.
// Step cost model (validated on R1/R2/R6 counters): step = MFMA_issue/SIMD
// + VALU_issue + LDS + serial_chain, nearly additive (phase-locked waves).
// This version minimizes every term:
//  - h@Uk only in-step: 16 MFMAs/wave (m-broadcast, all 4 gates of
//    u = 16w+c in-lane), TREE-split depth 2 (accA = kc0+kc1, accB = kc2+kc3).
//  - x@Wk precomputed per 16-step chunk into LDS xg by ALL waves in a
//    2-phase spike (tin==8: tiles 0,1; tin==9: tiles 2,3) -> no per-step
//    wave imbalance (R6's stagger mistake), +85 cyc peak, ~11/step avg.
//  - next step's acc-init prefetched into registers (xgn) at the END of
//    each step -> xg read is off the critical path (R2's mistake).
//  - acc-init writes element 0 only (the only element ever read; rows are
//    broadcast-equal): 2 movs/tile instead of 8. Elements 1-3 carry
//    harmless stale garbage (finite, linear drift, never read).
//  - x staged in a 2-chunk swizzled LDS ring; global float2 loads issued
//    at tin==0 (chunk k+2), landed tin==14; the per-step barrier is
//    lgkm-only (never drains vmcnt) so they stay in flight.
__global__ __launch_bounds__(512, 2)
void lstm_mfma(const float* __restrict__ x,     // [B,T,D]
               const float* __restrict__ cond,  // [B,COND]
               const float* __restrict__ Wc,    // [COND,U]
               const float* __restrict__ bc,    // [U]
               const float* __restrict__ Wk,    // [D,4U]
               const float* __restrict__ Uk,    // [U,4U]
               const float* __restrict__ bias,  // [4U]
               float* __restrict__ out) {       // [B,U]
    const int b    = blockIdx.x;
    const int tid  = threadIdx.x;
    const int lane = tid & 63;
    const int w    = tid >> 6;     // wave 0..7
    const int q    = lane >> 4;    // quad 0..3
    const int c    = lane & 15;
    const int u    = 16 * w + c;   // this lane's state element

    __shared__ __align__(16) char lds[kLds];

    // ---- B-frags: 4 tiles x 6 K-chunks, k = 32*kc + 8*q + j, col = 16t + c ----
    // kc 0..1 = Wk (K=64), kc 2..5 = Uk (K=128)
    f16x8 wfrag[4][6];
    float btile[4];
#pragma unroll
    for (int jt = 0; jt < 4; ++jt) {
        const int t   = w + 8 * jt;          // tile; jt = gate index (i,f,c~,o)
        const int col = 16 * t + c;
#pragma unroll
        for (int kc = 0; kc < 6; ++kc) {
            f16x8 f;
#pragma unroll
            for (int j = 0; j < 8; ++j) {
                const int k = 32 * kc + 8 * q + j;
                const float v = (k < kD) ? Wk[k * 512 + col]
                                         : Uk[(k - kD) * 512 + col];
                f[j] = (_Float16)v;
            }
            wfrag[jt][kc] = f;
        }
        btile[jt] = bias[col];
    }
#pragma unroll
    for (int jt = 0; jt < 4; ++jt)
#pragma unroll
        for (int kc = 0; kc < 6; ++kc) pin4_(wfrag[jt][kc]);

    // spike chunk-GEMM helpers: xg[slot] cols {16(w+8jt)+c} = bias +
    // xs[slot] @ Wk. A rows = 16 REAL timesteps; D rows 4q+r = timesteps.
    auto axload = [&](int slot, f16x8* ax) {
#pragma unroll
        for (int kc = 0; kc < 2; ++kc) {
            int byte = kXsOff + slot * kXsSlot + c * 128 + 64 * kc + 16 * q;
            byte ^= (c & 7) << 4;
            ax[kc] = *(const f16x8*)(lds + byte);
        }
    };
    auto xghalf = [&](int slot, int jt0, int jt1, const f16x8* ax) {
#pragma unroll
        for (int jt = jt0; jt < jt1; ++jt) {
            f32x4 acc = (f32x4){btile[jt], btile[jt], btile[jt], btile[jt]};
            acc = __builtin_amdgcn_mfma_f32_16x16x32_f16(ax[0], wfrag[jt][0], acc, 0, 0, 0);
            acc = __builtin_amdgcn_mfma_f32_16x16x32_f16(ax[1], wfrag[jt][1], acc, 0, 0, 0);
            float* dst = (float*)(lds + kXgOff + slot * kXgSlot);
            const int col = 16 * (w + 8 * jt) + c;
#pragma unroll
            for (int r = 0; r < 4; ++r)
                dst[(4 * q + r) * kXGS + col] = acc[r];
        }
    };

    // x chunk staging: thread owns floats [2tid, 2tid+1] of each 1024-float chunk
    const int srow = tid >> 5;             // timestep row in chunk
    const int sd   = (tid & 31) * 2;       // d offset
    const float* xb = x + (size_t)b * kT * kD;
    auto land = [&](int slot, float2 v) {
        int byte = kXsOff + slot * kXsSlot + srow * 128 + sd * 2;
        byte ^= (srow & 7) << 4;
        *(f16x2*)(lds + byte) = (f16x2){(_Float16)v.x, (_Float16)v.y};
    };

    // ---- initial state: c0 = h0 = bc[u] + cond[b,:] @ Wc[:,u] ----
    float c_reg;
    {
        float a = bc[u];
        const float* cr = cond + (size_t)b * kCOND;
#pragma unroll
        for (int kk = 0; kk < kCOND; ++kk) a = fmaf(cr[kk], Wc[kk * kU + u], a);
        c_reg = a;
        if (q == 0) *(_Float16*)(lds + kHOff + 2 * u) = (_Float16)a;
    }

    // ---- prologue: chunk 0 staged + GEMMed (all tiles), chunk 1 staged ----
    land(0, *(const float2*)&xb[2 * tid]);
    __syncthreads();
    {
        f16x8 ax0[2];
        axload(0, ax0);
        xghalf(0, 0, 4, ax0);
    }
    land(1, *(const float2*)&xb[1024 + 2 * tid]);
    __syncthreads();

    // step-0 acc-init (this wave's own xg cols, row 0 of slot 0)
    float xgn[4];
#pragma unroll
    for (int jt = 0; jt < 4; ++jt)
        xgn[jt] = *(const float*)(lds + kXgOff + (16 * (w + 8 * jt) + c) * 4);

    float  h_out = 0.0f;
    float2 xpf;
    f16x8  axs[2];                 // spike A-frags, live tin 8..9
    f32x4  accA[4], accB[4];       // persistent; only element 0 is ever read
#pragma unroll
    for (int jt = 0; jt < 4; ++jt) {
        accA[jt] = (f32x4){0.0f, 0.0f, 0.0f, 0.0f};
        accB[jt] = (f32x4){0.0f, 0.0f, 0.0f, 0.0f};
    }

#pragma unroll 1
    for (int t = 0; t < kT; ++t) {
        const int tin = t & (kCH - 1);
        const int k   = t >> 4;
        const int cur = t & 1;

        // h A-frags first: the only step-critical LDS reads (quad-broadcast)
        f16x8 afh[4];
#pragma unroll
        for (int kc = 0; kc < 4; ++kc)
            afh[kc] = *(const f16x8*)(lds + kHOff + cur * 256 + 64 * kc + 16 * q);

        // issue next chunk's global loads (landed at tin==14)
        if (tin == 0) {
            int kn = k + 2; if (kn > 127) kn = 127;   // tail: staged, never used
            xpf = *(const float2*)&xb[(size_t)kn * 1024 + 2 * tid];
        }

        // acc-init: element 0 only (rows are broadcast-equal; only [0] is read)
#pragma unroll
        for (int jt = 0; jt < 4; ++jt) {
            accA[jt][0] = xgn[jt];
            accB[jt][0] = 0.0f;
        }
        // h-MFMA tree, depth 2: accA = kc0+kc1, accB = kc2+kc3
#pragma unroll
        for (int jt = 0; jt < 4; ++jt)
            accA[jt] = __builtin_amdgcn_mfma_f32_16x16x32_f16(
                afh[0], wfrag[jt][2], accA[jt], 0, 0, 0);
#pragma unroll
        for (int jt = 0; jt < 4; ++jt)
            accB[jt] = __builtin_amdgcn_mfma_f32_16x16x32_f16(
                afh[2], wfrag[jt][4], accB[jt], 0, 0, 0);
#pragma unroll
        for (int jt = 0; jt < 4; ++jt)
            accA[jt] = __builtin_amdgcn_mfma_f32_16x16x32_f16(
                afh[1], wfrag[jt][3], accA[jt], 0, 0, 0);
#pragma unroll
        for (int jt = 0; jt < 4; ++jt)
            accB[jt] = __builtin_amdgcn_mfma_f32_16x16x32_f16(
                afh[3], wfrag[jt][5], accB[jt], 0, 0, 0);

        // gates (in-lane): g = accA[0] + accB[0]
        const float iv = sig_(accA[0][0] + accB[0][0]);
        const float fv = sig_(accA[1][0] + accB[1][0]);
        const float cb = tanh_(accA[2][0] + accB[2][0]);
        const float ov = sig_(accA[3][0] + accB[3][0]);
        c_reg = fmaf(fv, c_reg, iv * cb);
        h_out = ov * tanh_(c_reg);
        if (q == 0)
            *(_Float16*)(lds + kHOff + (cur ^ 1) * 256 + 2 * u) = (_Float16)h_out;

        // 2-phase all-wave spike: chunk k+1's xg (independent of the h chain)
        if (tin == 8 && k < 127) {
            axload((k + 1) & 1, axs);
            xghalf((k + 1) & 1, 0, 2, axs);
        } else if (tin == 9 && k < 127) {
            xghalf((k + 1) & 1, 2, 4, axs);
        }

        // land the prefetched x chunk (k+2) into xs[k&1]
        if (tin == kCH - 2) land(k & 1, xpf);

        // prefetch next step's acc-init into registers (latency buried
        // under the barrier; consumed after it)
        if (t < kT - 1) {
            const int t1 = t + 1;
            const char* src = lds + kXgOff + (((t1 >> 4) & 1) ? kXgSlot : 0) +
                              ((t1 & 15) * kXGS) * 4 + (16 * w + c) * 4;
#pragma unroll
            for (int jt = 0; jt < 4; ++jt)
                xgn[jt] = *(const float*)(src + jt * 512);   // 128 floats/tile
        }

        // LDS-only barrier: never drains vmcnt -> x prefetch stays in flight
        asm volatile("s_waitcnt lgkmcnt(0)\n\ts_barrier" ::: "memory");
    }

    if (q == 0) out[(size_t)b * kU + u] = h_out;
}

extern "C" void kernel_launch(void* const* d_in, const int* in_sizes, int n_in,
                              void* d_out, int out_size, void* d_ws, size_t ws_size,
                              hipStream_t stream) {
    const float* x    = (const float*)d_in[0];
    const float* cond = (const float*)d_in[1];
    const float* Wc   = (const float*)d_in[2];
    const float* bc   = (const float*)d_in[3];
    const float* Wk   = (const float*)d_in[4];
    const float* Uk   = (const float*)d_in[5];
    const float* b    = (const float*)d_in[6];
    float* out = (float*)d_out;

    lstm_mfma<<<dim3(kB), dim3(512), 0, stream>>>(x, cond, Wc, bc, Wk, Uk, b, out);
}

// Round 8
// 1250.245 us; speedup vs baseline: 1.4430x; 1.4430x over previous
//
#include <hip/hip_runtime.h>
#include <math.h>

// B=256, T=2048, D=64, U=128, 4U=512, COND=32
namespace {
constexpr int kB    = 256;
constexpr int kT    = 2048;
constexpr int kD    = 64;
constexpr int kU    = 128;
constexpr int kCOND = 32;
constexpr int kCH   = 16;    // timesteps per x chunk
constexpr int kXGS  = 516;   // xg row stride in floats (R2-measured: 0 conflicts)
}

typedef _Float16 f16x8 __attribute__((ext_vector_type(8)));
typedef float    f32x4 __attribute__((ext_vector_type(4)));

// VALU-diet activations: v_rcp_f32 (~1e-7 rel err) instead of the ~8-instr
// IEEE division expansion. Per step this cuts ~65 -> ~28 VALU instrs of
// gate math per lane (the R1/R2/R7 counter ledger shows step time =
// MFMA_issue + VALU_issue, additive, so VALU instr count is a direct lever).
__device__ __forceinline__ float rcp_(float x) {
    return __builtin_amdgcn_rcpf(x);
}
__device__ __forceinline__ float sig_(float z) {
    return rcp_(1.0f + __expf(-z));
}
__device__ __forceinline__ float tanh_(float z) {
    const float e = __expf(-2.0f * fabsf(z));          // e = exp(-2|z|)
    const float t = 1.0f - 2.0f * e * rcp_(1.0f + e);  // (1-e)/(1+e)
    return copysignf(t, z);
}
// pin a 16B fragment so the allocator cannot rematerialize its global loads
__device__ __forceinline__ void pin4_(f16x8& w) {
    f32x4 t = __builtin_bit_cast(f32x4, w);
    asm volatile("" : "+v"(t));
    w = __builtin_bit_cast(f16x8, t);
}

// One WG (512 thr = 8 waves) per batch element, persistent over T steps.
// Structure = R2 (best-measured conflict-free split design), unchanged:
//  - x@Wk computed densely per 16-step chunk (M = 16 real timesteps,
//    all-wave spike at tin==8, 8 MFMAs/wave) into LDS xg (+bias).
//  - per-step h@Uk via m-broadcast (16 MFMAs/wave, all 4 gates of
//    u = 16w+c land in-lane), acc initialized from an in-step xg scalar
//    read (parallel to the afh reads -> same critical path as R1).
//  - fresh accumulators every step (no cross-step MFMA register dep).
//  - x staged in a 2-chunk swizzled LDS ring; float2 loads issued at
//    tin==0, landed tin==7, GEMMed tin==8; per-step barrier is lgkm-only
//    so the global loads stay in flight across it.
// Only change vs R2: the rcp_-diet gates above.
__global__ __launch_bounds__(512, 2)
void lstm_mfma(const float* __restrict__ x,     // [B,T,D]
               const float* __restrict__ cond,  // [B,COND]
               const float* __restrict__ Wc,    // [COND,U]
               const float* __restrict__ bc,    // [U]
               const float* __restrict__ Wk,    // [D,4U]
               const float* __restrict__ Uk,    // [U,4U]
               const float* __restrict__ bias,  // [4U]
               float* __restrict__ out) {       // [B,U]
    const int b    = blockIdx.x;
    const int tid  = threadIdx.x;
    const int lane = tid & 63;
    const int w    = tid >> 6;     // wave 0..7
    const int q    = lane >> 4;    // quad 0..3
    const int c    = lane & 15;
    const int u    = 16 * w + c;   // this lane's state element

    __shared__ __align__(16) _Float16 hbuf[2][kU];        // h double-buffer
    __shared__ __align__(16) _Float16 xs[2][kCH * kD];    // x chunk (swizzled)
    __shared__ __align__(16) float    xg[2][kCH][kXGS];   // x@Wk + bias

    // ---- B-frags: 4 tiles x 6 K-chunks, k = 32*kc + 8*q + j, col = 16t + c ----
    // kc 0..1 = Wk (K=64), kc 2..5 = Uk (K=128)
    f16x8 wfrag[4][6];
    float btile[4];
#pragma unroll
    for (int jt = 0; jt < 4; ++jt) {
        const int t   = w + 8 * jt;          // tile; jt = gate index (i,f,c~,o)
        const int col = 16 * t + c;
#pragma unroll
        for (int kc = 0; kc < 6; ++kc) {
            f16x8 f;
#pragma unroll
            for (int j = 0; j < 8; ++j) {
                const int k = 32 * kc + 8 * q + j;
                const float v = (k < kD) ? Wk[k * 512 + col]
                                         : Uk[(k - kD) * 512 + col];
                f[j] = (_Float16)v;
            }
            wfrag[jt][kc] = f;
        }
        btile[jt] = bias[col];
    }
#pragma unroll
    for (int jt = 0; jt < 4; ++jt)
#pragma unroll
        for (int kc = 0; kc < 6; ++kc) pin4_(wfrag[jt][kc]);

    // chunk-GEMM: xg[slot] = xs[slot] @ Wk + bias   (M = 16 timesteps)
    // A-frag: lane holds A[m = lane&15][k = 8q + j + 32kc] -> read row c.
    // D-frag: D[row = 4q + r][col = 16*tile + c].
    auto xgemm = [&](int slot) {
        f16x8 ax[2];
#pragma unroll
        for (int kc = 0; kc < 2; ++kc) {
            int byte = c * 128 + 64 * kc + 16 * q;
            byte ^= (c & 7) << 4;
            ax[kc] = *(const f16x8*)((const char*)&xs[slot][0] + byte);
        }
        f32x4 accx[4];
#pragma unroll
        for (int jt = 0; jt < 4; ++jt)
            accx[jt] = (f32x4){btile[jt], btile[jt], btile[jt], btile[jt]};
#pragma unroll
        for (int kc = 0; kc < 2; ++kc)
#pragma unroll
            for (int jt = 0; jt < 4; ++jt)
                accx[jt] = __builtin_amdgcn_mfma_f32_16x16x32_f16(
                    ax[kc], wfrag[jt][kc], accx[jt], 0, 0, 0);
#pragma unroll
        for (int jt = 0; jt < 4; ++jt) {
            const int col = 16 * (w + 8 * jt) + c;
#pragma unroll
            for (int r = 0; r < 4; ++r)
                xg[slot][4 * q + r][col] = accx[jt][r];
        }
    };

    // ---- initial state: c0 = h0 = bc[u] + cond[b,:] @ Wc[:,u] ----
    float c_reg;
    {
        float a = bc[u];
        const float* cr = cond + b * kCOND;
#pragma unroll
        for (int kk = 0; kk < kCOND; ++kk) a = fmaf(cr[kk], Wc[kk * kU + u], a);
        c_reg = a;
        if (q == 0) hbuf[0][u] = (_Float16)a;
    }

    const float* xb = x + (size_t)b * kT * kD;

    // ---- stage chunk 0 (t = 0..15) into xs[0] (swizzled) ----
    {
        const int row = tid >> 5;            // timestep within chunk
        float2 v = *(const float2*)&xb[(size_t)row * kD + (tid & 31) * 2];
        int byte = row * 128 + (tid & 31) * 4;
        byte ^= (row & 7) << 4;
        _Float16* p = (_Float16*)((char*)&xs[0][0] + byte);
        p[0] = (_Float16)v.x;
        p[1] = (_Float16)v.y;
    }
    __syncthreads();
    xgemm(0);                 // xg[0] = chunk-0 preacts + bias
    __syncthreads();

    float  h_out = 0.0f;
    float2 xpf   = make_float2(0.0f, 0.0f);  // in-flight chunk prefetch

#pragma unroll 1
    for (int t = 0; t < kT; ++t) {
        const int tin   = t & (kCH - 1);
        const int chunk = t >> 4;
        const int cur   = t & 1;
        const int csl   = chunk & 1;

        // issue next chunk's global loads (written to xs at tin==7)
        if (tin == 0) {
            int tr = t + kCH + (tid >> 5);
            if (tr > kT - 1) tr = kT - 1;    // tail clamp: staged, never read
            xpf = *(const float2*)&xb[(size_t)tr * kD + (tid & 31) * 2];
        }

        // h A-frags: broadcast reads (16 c-lanes of a quad read the same 16B)
        f16x8 afh[4];
#pragma unroll
        for (int kc = 0; kc < 4; ++kc)
            afh[kc] = *(const f16x8*)&hbuf[cur][32 * kc + 8 * q];

        // acc init = xg (x-preact + bias), splat so D stays row-constant
        f32x4 acc[4];
#pragma unroll
        for (int jt = 0; jt < 4; ++jt) {
            const float g = xg[csl][tin][16 * (w + 8 * jt) + c];
            acc[jt] = (f32x4){g, g, g, g};
        }

#pragma unroll
        for (int kc = 0; kc < 4; ++kc)
#pragma unroll
            for (int jt = 0; jt < 4; ++jt)
                acc[jt] = __builtin_amdgcn_mfma_f32_16x16x32_f16(
                    afh[kc], wfrag[jt][2 + kc], acc[jt], 0, 0, 0);

        // gates: D is row-constant -> reg 0 of each tile = G[16t + c]
        const float iv = sig_(acc[0][0]);
        const float fv = sig_(acc[1][0]);
        const float cb = tanh_(acc[2][0]);
        const float ov = sig_(acc[3][0]);
        c_reg = fmaf(fv, c_reg, iv * cb);
        h_out = ov * tanh_(c_reg);

        if (q == 0) hbuf[cur ^ 1][u] = (_Float16)h_out;   // h_{t+1}

        // mid-chunk: land the prefetched x chunk into xs (swizzled)
        if (tin == 7) {
            const int row = tid >> 5;
            int byte = row * 128 + (tid & 31) * 4;
            byte ^= (row & 7) << 4;
            _Float16* p = (_Float16*)((char*)&xs[csl ^ 1][0] + byte);
            p[0] = (_Float16)xpf.x;
            p[1] = (_Float16)xpf.y;
        }
        // then run the dense chunk-GEMM for the next chunk's preacts
        if (tin == 8) xgemm(csl ^ 1);

        // LDS-only barrier: do NOT drain vmcnt -> prefetch stays in flight
        asm volatile("s_waitcnt lgkmcnt(0)\n\ts_barrier" ::: "memory");
    }

    if (q == 0) out[b * kU + u] = h_out;
}

extern "C" void kernel_launch(void* const* d_in, const int* in_sizes, int n_in,
                              void* d_out, int out_size, void* d_ws, size_t ws_size,
                              hipStream_t stream) {
    const float* x    = (const float*)d_in[0];
    const float* cond = (const float*)d_in[1];
    const float* Wc   = (const float*)d_in[2];
    const float* bc   = (const float*)d_in[3];
    const float* Wk   = (const float*)d_in[4];
    const float* Uk   = (const float*)d_in[5];
    const float* b    = (const float*)d_in[6];
    float* out = (float*)d_out;

    lstm_mfma<<<dim3(kB), dim3(512), 0, stream>>>(x, cond, Wc, bc, Wk, Uk, b, out);
}

// Round 9
// 1091.671 us; speedup vs baseline: 1.6526x; 1.1453x over previous
//
#include <hip/hip_runtime.h>
#include <math.h>

// B=256, T=2048, D=64, U=128, 4U=512, COND=32
namespace {
constexpr int kB    = 256;
constexpr int kT    = 2048;
constexpr int kD    = 64;
constexpr int kU    = 128;
constexpr int kCOND = 32;
constexpr int kCH   = 16;    // timesteps per x chunk
constexpr int kXGS  = 516;   // xg row stride in floats (R2/R8-measured: 0 conflicts)
}

typedef _Float16 f16x8 __attribute__((ext_vector_type(8)));
typedef float    f32x4 __attribute__((ext_vector_type(4)));

// VALU-diet activations (R8: -400 cyc/SIMD-step vs IEEE division expansion).
__device__ __forceinline__ float rcp_(float x) {
    return __builtin_amdgcn_rcpf(x);
}
__device__ __forceinline__ float sig_(float z) {
    return rcp_(1.0f + __expf(-z));
}
__device__ __forceinline__ float tanh_(float z) {
    const float e = __expf(-2.0f * fabsf(z));          // e = exp(-2|z|)
    const float t = 1.0f - 2.0f * e * rcp_(1.0f + e);  // (1-e)/(1+e)
    return copysignf(t, z);
}
// pin a 16B fragment so the allocator cannot rematerialize its global loads
__device__ __forceinline__ void pin4_(f16x8& w) {
    f32x4 t = __builtin_bit_cast(f32x4, w);
    asm volatile("" : "+v"(t));
    w = __builtin_bit_cast(f16x8, t);
}

// One WG (512 thr = 8 waves) per batch element, persistent over T steps.
// Structure = R8 (measured 1250 us; step ledger: MFMA-pipe 580 cyc + pure
// VALU ~100 + LDS ~150 + serial recurrence chain ~630). R9 trims issue:
//  (a) persistent accumulators with element-0-only init: only acc[jt][0]
//      (D row 4q, the broadcast-equal row we read) needs the xg preact;
//      elements 1-3 carry stale finite garbage (never read; R7 validated
//      numerically). The xg ds_read lands directly in the acc register --
//      kills 16 splat v_movs per step.
//  (b) #pragma unroll 2: folds cur to constants, halves loop bookkeeping.
// Everything else byte-identical to R8:
//  - x@Wk densely per 16-step chunk (all-wave spike at tin==8) into LDS xg.
//  - per-step h@Uk m-broadcast (16 MFMAs/wave; all 4 gates of u=16w+c
//    in-lane), rcp-diet gates, swizzled 2-chunk x ring, lgkm-only barrier.
__global__ __launch_bounds__(512, 2)
void lstm_mfma(const float* __restrict__ x,     // [B,T,D]
               const float* __restrict__ cond,  // [B,COND]
               const float* __restrict__ Wc,    // [COND,U]
               const float* __restrict__ bc,    // [U]
               const float* __restrict__ Wk,    // [D,4U]
               const float* __restrict__ Uk,    // [U,4U]
               const float* __restrict__ bias,  // [4U]
               float* __restrict__ out) {       // [B,U]
    const int b    = blockIdx.x;
    const int tid  = threadIdx.x;
    const int lane = tid & 63;
    const int w    = tid >> 6;     // wave 0..7
    const int q    = lane >> 4;    // quad 0..3
    const int c    = lane & 15;
    const int u    = 16 * w + c;   // this lane's state element

    __shared__ __align__(16) _Float16 hbuf[2][kU];        // h double-buffer
    __shared__ __align__(16) _Float16 xs[2][kCH * kD];    // x chunk (swizzled)
    __shared__ __align__(16) float    xg[2][kCH][kXGS];   // x@Wk + bias

    // ---- B-frags: 4 tiles x 6 K-chunks, k = 32*kc + 8*q + j, col = 16t + c ----
    // kc 0..1 = Wk (K=64), kc 2..5 = Uk (K=128)
    f16x8 wfrag[4][6];
    float btile[4];
#pragma unroll
    for (int jt = 0; jt < 4; ++jt) {
        const int t   = w + 8 * jt;          // tile; jt = gate index (i,f,c~,o)
        const int col = 16 * t + c;
#pragma unroll
        for (int kc = 0; kc < 6; ++kc) {
            f16x8 f;
#pragma unroll
            for (int j = 0; j < 8; ++j) {
                const int k = 32 * kc + 8 * q + j;
                const float v = (k < kD) ? Wk[k * 512 + col]
                                         : Uk[(k - kD) * 512 + col];
                f[j] = (_Float16)v;
            }
            wfrag[jt][kc] = f;
        }
        btile[jt] = bias[col];
    }
#pragma unroll
    for (int jt = 0; jt < 4; ++jt)
#pragma unroll
        for (int kc = 0; kc < 6; ++kc) pin4_(wfrag[jt][kc]);

    // chunk-GEMM: xg[slot] = xs[slot] @ Wk + bias   (M = 16 timesteps)
    auto xgemm = [&](int slot) {
        f16x8 ax[2];
#pragma unroll
        for (int kc = 0; kc < 2; ++kc) {
            int byte = c * 128 + 64 * kc + 16 * q;
            byte ^= (c & 7) << 4;
            ax[kc] = *(const f16x8*)((const char*)&xs[slot][0] + byte);
        }
        f32x4 accx[4];
#pragma unroll
        for (int jt = 0; jt < 4; ++jt)
            accx[jt] = (f32x4){btile[jt], btile[jt], btile[jt], btile[jt]};
#pragma unroll
        for (int kc = 0; kc < 2; ++kc)
#pragma unroll
            for (int jt = 0; jt < 4; ++jt)
                accx[jt] = __builtin_amdgcn_mfma_f32_16x16x32_f16(
                    ax[kc], wfrag[jt][kc], accx[jt], 0, 0, 0);
#pragma unroll
        for (int jt = 0; jt < 4; ++jt) {
            const int col = 16 * (w + 8 * jt) + c;
#pragma unroll
            for (int r = 0; r < 4; ++r)
                xg[slot][4 * q + r][col] = accx[jt][r];
        }
    };

    // ---- initial state: c0 = h0 = bc[u] + cond[b,:] @ Wc[:,u] ----
    float c_reg;
    {
        float a = bc[u];
        const float* cr = cond + b * kCOND;
#pragma unroll
        for (int kk = 0; kk < kCOND; ++kk) a = fmaf(cr[kk], Wc[kk * kU + u], a);
        c_reg = a;
        if (q == 0) hbuf[0][u] = (_Float16)a;
    }

    const float* xb = x + (size_t)b * kT * kD;

    // ---- stage chunk 0 (t = 0..15) into xs[0] (swizzled) ----
    {
        const int row = tid >> 5;            // timestep within chunk
        float2 v = *(const float2*)&xb[(size_t)row * kD + (tid & 31) * 2];
        int byte = row * 128 + (tid & 31) * 4;
        byte ^= (row & 7) << 4;
        _Float16* p = (_Float16*)((char*)&xs[0][0] + byte);
        p[0] = (_Float16)v.x;
        p[1] = (_Float16)v.y;
    }
    __syncthreads();
    xgemm(0);                 // xg[0] = chunk-0 preacts + bias
    __syncthreads();

    float  h_out = 0.0f;
    float2 xpf   = make_float2(0.0f, 0.0f);  // in-flight chunk prefetch
    f32x4  acc[4];                           // persistent; only [0] meaningful
#pragma unroll
    for (int jt = 0; jt < 4; ++jt)
        acc[jt] = (f32x4){0.0f, 0.0f, 0.0f, 0.0f};

#pragma unroll 2
    for (int t = 0; t < kT; ++t) {
        const int tin   = t & (kCH - 1);
        const int chunk = t >> 4;
        const int cur   = t & 1;
        const int csl   = chunk & 1;

        // issue next chunk's global loads (written to xs at tin==7)
        if (tin == 0) {
            int tr = t + kCH + (tid >> 5);
            if (tr > kT - 1) tr = kT - 1;    // tail clamp: staged, never read
            xpf = *(const float2*)&xb[(size_t)tr * kD + (tid & 31) * 2];
        }

        // h A-frags: broadcast reads (16 c-lanes of a quad read the same 16B)
        f16x8 afh[4];
#pragma unroll
        for (int kc = 0; kc < 4; ++kc)
            afh[kc] = *(const f16x8*)&hbuf[cur][32 * kc + 8 * q];

        // acc init: element 0 only (the broadcast-equal row we read).
        // Elements 1-3 keep stale finite values from the previous step --
        // never read, numerically harmless (R7-validated).
#pragma unroll
        for (int jt = 0; jt < 4; ++jt)
            acc[jt][0] = xg[csl][tin][16 * (w + 8 * jt) + c];

#pragma unroll
        for (int kc = 0; kc < 4; ++kc)
#pragma unroll
            for (int jt = 0; jt < 4; ++jt)
                acc[jt] = __builtin_amdgcn_mfma_f32_16x16x32_f16(
                    afh[kc], wfrag[jt][2 + kc], acc[jt], 0, 0, 0);

        // gates: D is row-constant -> reg 0 of each tile = G[16t + c]
        const float iv = sig_(acc[0][0]);
        const float fv = sig_(acc[1][0]);
        const float cb = tanh_(acc[2][0]);
        const float ov = sig_(acc[3][0]);
        c_reg = fmaf(fv, c_reg, iv * cb);
        h_out = ov * tanh_(c_reg);

        if (q == 0) hbuf[cur ^ 1][u] = (_Float16)h_out;   // h_{t+1}

        // mid-chunk: land the prefetched x chunk into xs (swizzled)
        if (tin == 7) {
            const int row = tid >> 5;
            int byte = row * 128 + (tid & 31) * 4;
            byte ^= (row & 7) << 4;
            _Float16* p = (_Float16*)((char*)&xs[csl ^ 1][0] + byte);
            p[0] = (_Float16)xpf.x;
            p[1] = (_Float16)xpf.y;
        }
        // then run the dense chunk-GEMM for the next chunk's preacts
        if (tin == 8) xgemm(csl ^ 1);

        // LDS-only barrier: do NOT drain vmcnt -> prefetch stays in flight
        asm volatile("s_waitcnt lgkmcnt(0)\n\ts_barrier" ::: "memory");
    }

    if (q == 0) out[b * kU + u] = h_out;
}

extern "C" void kernel_launch(void* const* d_in, const int* in_sizes, int n_in,
                              void* d_out, int out_size, void* d_ws, size_t ws_size,
                              hipStream_t stream) {
    const float* x    = (const float*)d_in[0];
    const float* cond = (const float*)d_in[1];
    const float* Wc   = (const float*)d_in[2];
    const float* bc   = (const float*)d_in[3];
    const float* Wk   = (const float*)d_in[4];
    const float* Uk   = (const float*)d_in[5];
    const float* b    = (const float*)d_in[6];
    float* out = (float*)d_out;

    lstm_mfma<<<dim3(kB), dim3(512), 0, stream>>>(x, cond, Wc, bc, Wk, Uk, b, out);
}